// Round 1
// baseline (1778.624 us; speedup 1.0000x reference)
//
#include <hip/hip_runtime.h>
#include <hip/hip_bf16.h>
#include <stdint.h>

#define NTOK 8192
#define DDIM 1024
#define HDIM 4096
#define NEXP 8

#define BM 128
#define BN 128
#define BK 32
#define LDK 40   // BK + 8 pad (keeps 16B alignment, breaks bank periodicity)

typedef __attribute__((ext_vector_type(4))) float f32x4;
typedef __attribute__((ext_vector_type(8))) short s16x8;
typedef __attribute__((ext_vector_type(8))) unsigned short u16x8;

__device__ __forceinline__ unsigned short f2bf(float f) {
  union { float f; unsigned int u; } v; v.f = f;
  unsigned int u = v.u;
  u += 0x7FFFu + ((u >> 16) & 1u);   // round-to-nearest-even
  return (unsigned short)(u >> 16);
}

// ---------------- gate + top-1 routing ----------------
__global__ __launch_bounds__(256) void gate_kernel(
    const float* __restrict__ x, const float* __restrict__ Wg,
    const float* __restrict__ bg, int* __restrict__ counts,
    int* __restrict__ lists) {
  const int lane = threadIdx.x & 63;
  const int tok = blockIdx.x * 4 + (threadIdx.x >> 6);
  const float* xr = x + (size_t)tok * DDIM;
  double acc[NEXP];
#pragma unroll
  for (int e = 0; e < NEXP; ++e) acc[e] = 0.0;
#pragma unroll 4
  for (int it = 0; it < DDIM / 64; ++it) {
    const int d = it * 64 + lane;
    const float xv = xr[d];
    const f32x4 w0 = *(const f32x4*)(Wg + (size_t)d * NEXP);
    const f32x4 w1 = *(const f32x4*)(Wg + (size_t)d * NEXP + 4);
#pragma unroll
    for (int j = 0; j < 4; ++j) {
      acc[j]     += (double)xv * (double)w0[j];
      acc[4 + j] += (double)xv * (double)w1[j];
    }
  }
#pragma unroll
  for (int e = 0; e < NEXP; ++e) {
    double v = acc[e];
#pragma unroll
    for (int off = 32; off > 0; off >>= 1) v += __shfl_xor(v, off, 64);
    acc[e] = v;
  }
  if (lane == 0) {
    int best = 0;
    double bv = acc[0] + (double)bg[0];
#pragma unroll
    for (int e = 1; e < NEXP; ++e) {
      const double v = acc[e] + (double)bg[e];
      if (v > bv) { bv = v; best = e; }   // strict > : first max wins (np argmax)
    }
    const int pos = atomicAdd(&counts[best], 1);
    lists[best * NTOK + pos] = tok;
  }
}

// ---------------- grouped GEMM 1: H = relu(X @ W1[e] + b1[e]) ----------------
__global__ __launch_bounds__(256) void ffn1_kernel(
    const float* __restrict__ x, const float* __restrict__ W1,
    const float* __restrict__ b1, const int* __restrict__ counts,
    const int* __restrict__ lists, unsigned short* __restrict__ Hbuf) {
  const int e = blockIdx.z;
  const int cnt = counts[e];
  const int row0 = blockIdx.x * BM;
  if (row0 >= cnt) return;
  const int col0 = blockIdx.y * BN;

  __shared__ unsigned short As[BM][LDK];
  __shared__ unsigned short Bs[BN][LDK];
  __shared__ int toks[BM];

  const int tid = threadIdx.x;
  const int lane = tid & 63;
  const int wave = tid >> 6;
  const int wm = wave >> 1;
  const int wn = wave & 1;

  if (tid < BM) {
    const int r = row0 + tid;
    toks[tid] = (r < cnt) ? lists[e * NTOK + r] : -1;
  }
  __syncthreads();

  const float* __restrict__ W1e = W1 + (size_t)e * DDIM * HDIM;

  f32x4 acc[4][4];
#pragma unroll
  for (int m = 0; m < 4; ++m)
#pragma unroll
    for (int n = 0; n < 4; ++n)
      acc[m][n] = f32x4{0.f, 0.f, 0.f, 0.f};

  const int arow = tid >> 1;
  const int akh = (tid & 1) * 16;
  const int mytok = toks[arow];
  const float* __restrict__ asrc = (mytok >= 0) ? (x + (size_t)mytok * DDIM + akh) : x;

  const int bn = tid >> 1;          // output column this thread stages
  const int bkh = (tid & 1) * 16;   // k-half
  const float* __restrict__ bsrc = W1e + (size_t)bkh * HDIM + col0 + bn;

  for (int k0 = 0; k0 < DDIM; k0 += BK) {
    // ---- stage A: gathered token rows, fp32 -> bf16, vectorized ----
    u16x8 p0 = {0,0,0,0,0,0,0,0}, p1 = {0,0,0,0,0,0,0,0};
    if (mytok >= 0) {
      const f32x4 f0 = *(const f32x4*)(asrc + k0);
      const f32x4 f1 = *(const f32x4*)(asrc + k0 + 4);
      const f32x4 f2 = *(const f32x4*)(asrc + k0 + 8);
      const f32x4 f3 = *(const f32x4*)(asrc + k0 + 12);
#pragma unroll
      for (int j = 0; j < 4; ++j) {
        p0[j] = f2bf(f0[j]); p0[4 + j] = f2bf(f1[j]);
        p1[j] = f2bf(f2[j]); p1[4 + j] = f2bf(f3[j]);
      }
    }
    // ---- stage B: W1 panel, coalesced k-strided loads, store k-contiguous ----
    u16x8 q0, q1;
    {
      const float* bp = bsrc + (size_t)k0 * HDIM;
#pragma unroll
      for (int kk = 0; kk < 8; ++kk) q0[kk] = f2bf(bp[(size_t)kk * HDIM]);
#pragma unroll
      for (int kk = 0; kk < 8; ++kk) q1[kk] = f2bf(bp[(size_t)(kk + 8) * HDIM]);
    }
    *(u16x8*)&As[arow][akh] = p0;
    *(u16x8*)&As[arow][akh + 8] = p1;
    *(u16x8*)&Bs[bn][bkh] = q0;
    *(u16x8*)&Bs[bn][bkh + 8] = q1;
    __syncthreads();

    s16x8 af[4], bf[4];
#pragma unroll
    for (int m = 0; m < 4; ++m)
      af[m] = *(const s16x8*)&As[wm * 64 + m * 16 + (lane & 15)][(lane >> 4) * 8];
#pragma unroll
    for (int n = 0; n < 4; ++n)
      bf[n] = *(const s16x8*)&Bs[wn * 64 + n * 16 + (lane & 15)][(lane >> 4) * 8];
#pragma unroll
    for (int m = 0; m < 4; ++m)
#pragma unroll
      for (int n = 0; n < 4; ++n)
        acc[m][n] = __builtin_amdgcn_mfma_f32_16x16x32_bf16(af[m], bf[n], acc[m][n], 0, 0, 0);
    __syncthreads();
  }

  // epilogue: relu(acc + b1) -> Hbuf[token][col] as bf16
#pragma unroll
  for (int n = 0; n < 4; ++n) {
    const int col = col0 + wn * 64 + n * 16 + (lane & 15);
    const float bv = b1[e * HDIM + col];
#pragma unroll
    for (int m = 0; m < 4; ++m) {
#pragma unroll
      for (int j = 0; j < 4; ++j) {
        const int r = wm * 64 + m * 16 + (lane >> 4) * 4 + j;
        const int tok = toks[r];
        if (tok >= 0) {
          const float v = fmaxf(acc[m][n][j] + bv, 0.f);
          Hbuf[(size_t)tok * HDIM + col] = f2bf(v);
        }
      }
    }
  }
}

// ---------------- grouped GEMM 2: out = H @ W2[e] + b2[e] ----------------
__global__ __launch_bounds__(256) void ffn2_kernel(
    const unsigned short* __restrict__ Hbuf, const float* __restrict__ W2,
    const float* __restrict__ b2, const int* __restrict__ counts,
    const int* __restrict__ lists, float* __restrict__ out) {
  const int e = blockIdx.z;
  const int cnt = counts[e];
  const int row0 = blockIdx.x * BM;
  if (row0 >= cnt) return;
  const int col0 = blockIdx.y * BN;

  __shared__ unsigned short As[BM][LDK];
  __shared__ unsigned short Bs[BN][LDK];
  __shared__ int toks[BM];

  const int tid = threadIdx.x;
  const int lane = tid & 63;
  const int wave = tid >> 6;
  const int wm = wave >> 1;
  const int wn = wave & 1;

  if (tid < BM) {
    const int r = row0 + tid;
    toks[tid] = (r < cnt) ? lists[e * NTOK + r] : -1;
  }
  __syncthreads();

  f32x4 acc[4][4];
#pragma unroll
  for (int m = 0; m < 4; ++m)
#pragma unroll
    for (int n = 0; n < 4; ++n)
      acc[m][n] = f32x4{0.f, 0.f, 0.f, 0.f};

  const int arow = tid >> 1;
  const int akh = (tid & 1) * 16;
  const int mytok = toks[arow];
  const unsigned short* __restrict__ asrc =
      (mytok >= 0) ? (Hbuf + (size_t)mytok * HDIM + akh) : Hbuf;

  const int bn = tid >> 1;
  const int bkh = (tid & 1) * 16;
  const float* __restrict__ bsrc =
      W2 + (size_t)e * HDIM * DDIM + (size_t)bkh * DDIM + col0 + bn;

  for (int k0 = 0; k0 < HDIM; k0 += BK) {
    u16x8 p0 = {0,0,0,0,0,0,0,0}, p1 = {0,0,0,0,0,0,0,0};
    if (mytok >= 0) {
      p0 = *(const u16x8*)(asrc + k0);
      p1 = *(const u16x8*)(asrc + k0 + 8);
    }
    u16x8 q0, q1;
    {
      const float* bp = bsrc + (size_t)k0 * DDIM;
#pragma unroll
      for (int kk = 0; kk < 8; ++kk) q0[kk] = f2bf(bp[(size_t)kk * DDIM]);
#pragma unroll
      for (int kk = 0; kk < 8; ++kk) q1[kk] = f2bf(bp[(size_t)(kk + 8) * DDIM]);
    }
    *(u16x8*)&As[arow][akh] = p0;
    *(u16x8*)&As[arow][akh + 8] = p1;
    *(u16x8*)&Bs[bn][bkh] = q0;
    *(u16x8*)&Bs[bn][bkh + 8] = q1;
    __syncthreads();

    s16x8 af[4], bf[4];
#pragma unroll
    for (int m = 0; m < 4; ++m)
      af[m] = *(const s16x8*)&As[wm * 64 + m * 16 + (lane & 15)][(lane >> 4) * 8];
#pragma unroll
    for (int n = 0; n < 4; ++n)
      bf[n] = *(const s16x8*)&Bs[wn * 64 + n * 16 + (lane & 15)][(lane >> 4) * 8];
#pragma unroll
    for (int m = 0; m < 4; ++m)
#pragma unroll
      for (int n = 0; n < 4; ++n)
        acc[m][n] = __builtin_amdgcn_mfma_f32_16x16x32_bf16(af[m], bf[n], acc[m][n], 0, 0, 0);
    __syncthreads();
  }

#pragma unroll
  for (int n = 0; n < 4; ++n) {
    const int col = col0 + wn * 64 + n * 16 + (lane & 15);
    const float bv = b2[e * DDIM + col];
#pragma unroll
    for (int m = 0; m < 4; ++m) {
#pragma unroll
      for (int j = 0; j < 4; ++j) {
        const int r = wm * 64 + m * 16 + (lane >> 4) * 4 + j;
        const int tok = toks[r];
        if (tok >= 0) out[(size_t)tok * DDIM + col] = acc[m][n][j] + bv;
      }
    }
  }
}

extern "C" void kernel_launch(void* const* d_in, const int* in_sizes, int n_in,
                              void* d_out, int out_size, void* d_ws, size_t ws_size,
                              hipStream_t stream) {
  (void)in_sizes; (void)n_in; (void)out_size;
  const float* x  = (const float*)d_in[0];
  const float* Wg = (const float*)d_in[1];
  const float* bg = (const float*)d_in[2];
  const float* W1 = (const float*)d_in[3];
  const float* b1 = (const float*)d_in[4];
  const float* W2 = (const float*)d_in[5];
  const float* b2 = (const float*)d_in[6];
  float* out = (float*)d_out;

  char* ws = (char*)d_ws;
  int* counts = (int*)ws;                                   // 8 ints
  int* lists  = (int*)(ws + 256);                           // [E][NTOK]
  unsigned short* Hbuf =
      (unsigned short*)(ws + 256 + (size_t)NEXP * NTOK * sizeof(int));  // [NTOK][HDIM] bf16
  const size_t need = 256 + (size_t)NEXP * NTOK * sizeof(int) +
                      (size_t)NTOK * HDIM * sizeof(unsigned short);
  if (ws_size < need) return;  // fail cleanly rather than corrupt memory

  hipMemsetAsync(counts, 0, 256, stream);
  gate_kernel<<<NTOK / 4, 256, 0, stream>>>(x, Wg, bg, counts, lists);
  ffn1_kernel<<<dim3(NTOK / BM, HDIM / BN, NEXP), 256, 0, stream>>>(
      x, W1, b1, counts, lists, Hbuf);
  ffn2_kernel<<<dim3(NTOK / BM, DDIM / BN, NEXP), 256, 0, stream>>>(
      Hbuf, W2, b2, counts, lists, out);
}

// Round 2
// 825.463 us; speedup vs baseline: 2.1547x; 2.1547x over previous
//
#include <hip/hip_runtime.h>
#include <hip/hip_bf16.h>
#include <stdint.h>

#define NTOK 8192
#define DDIM 1024
#define HDIM 4096
#define NEXP 8

typedef __attribute__((ext_vector_type(4))) float f32x4;
typedef __attribute__((ext_vector_type(8))) short s16x8;
typedef __attribute__((ext_vector_type(8))) unsigned short u16x8;

__device__ __forceinline__ unsigned short f2bf(float f) {
  union { float f; unsigned int u; } v; v.f = f;
  unsigned int u = v.u;
  u += 0x7FFFu + ((u >> 16) & 1u);   // round-to-nearest-even
  return (unsigned short)(u >> 16);
}

typedef __attribute__((address_space(3))) unsigned char lds_u8;
typedef const __attribute__((address_space(1))) unsigned char glb_u8;

__device__ __forceinline__ void load_lds16(const void* g, void* l) {
  __builtin_amdgcn_global_load_lds((glb_u8*)g, (lds_u8*)l, 16, 0, 0);
}

// ---------------- gate + top-1 routing ----------------
__global__ __launch_bounds__(256) void gate_kernel(
    const float* __restrict__ x, const float* __restrict__ Wg,
    const float* __restrict__ bg, int* __restrict__ counts,
    int* __restrict__ lists) {
  const int lane = threadIdx.x & 63;
  const int tok = blockIdx.x * 4 + (threadIdx.x >> 6);
  const float* xr = x + (size_t)tok * DDIM;
  double acc[NEXP];
#pragma unroll
  for (int e = 0; e < NEXP; ++e) acc[e] = 0.0;
#pragma unroll 4
  for (int it = 0; it < DDIM / 64; ++it) {
    const int d = it * 64 + lane;
    const float xv = xr[d];
    const f32x4 w0 = *(const f32x4*)(Wg + (size_t)d * NEXP);
    const f32x4 w1 = *(const f32x4*)(Wg + (size_t)d * NEXP + 4);
#pragma unroll
    for (int j = 0; j < 4; ++j) {
      acc[j]     += (double)xv * (double)w0[j];
      acc[4 + j] += (double)xv * (double)w1[j];
    }
  }
#pragma unroll
  for (int e = 0; e < NEXP; ++e) {
    double v = acc[e];
#pragma unroll
    for (int off = 32; off > 0; off >>= 1) v += __shfl_xor(v, off, 64);
    acc[e] = v;
  }
  if (lane == 0) {
    int best = 0;
    double bv = acc[0] + (double)bg[0];
#pragma unroll
    for (int e = 1; e < NEXP; ++e) {
      const double v = acc[e] + (double)bg[e];
      if (v > bv) { bv = v; best = e; }   // strict > : first max wins (np argmax)
    }
    const int pos = atomicAdd(&counts[best], 1);
    lists[best * NTOK + pos] = tok;
  }
}

// ---------------- fp32 -> bf16 elementwise (x) ----------------
__global__ __launch_bounds__(256) void conv_bf16_kernel(
    const float* __restrict__ in, unsigned short* __restrict__ out) {
  const size_t i = (size_t)(blockIdx.x * 256 + threadIdx.x) * 8;
  const f32x4 a = *(const f32x4*)(in + i);
  const f32x4 b = *(const f32x4*)(in + i + 4);
  u16x8 o;
#pragma unroll
  for (int j = 0; j < 4; ++j) { o[j] = f2bf(a[j]); o[4 + j] = f2bf(b[j]); }
  *(u16x8*)(out + i) = o;
}

// -------- transpose + convert: in [E][R][C] fp32 -> out [E][C][R] bf16 --------
__global__ __launch_bounds__(256) void transpose_conv_kernel(
    const float* __restrict__ in, unsigned short* __restrict__ out,
    int R, int C) {
  __shared__ unsigned short T[64][66];
  const int e = blockIdx.z;
  const float* ine = in + (size_t)e * R * C;
  unsigned short* oute = out + (size_t)e * C * R;
  const int c0 = blockIdx.x * 64, r0 = blockIdx.y * 64;
  const int t = threadIdx.x;
  const int tr = t >> 4, tc4 = (t & 15) * 4;
#pragma unroll
  for (int p = 0; p < 4; ++p) {
    const int r = tr + p * 16;
    const f32x4 v = *(const f32x4*)(ine + (size_t)(r0 + r) * C + c0 + tc4);
#pragma unroll
    for (int j = 0; j < 4; ++j) T[r][tc4 + j] = f2bf(v[j]);
  }
  __syncthreads();
#pragma unroll
  for (int p = 0; p < 4; ++p) {
    const int c = tr + p * 16;
    ushort4 o;
    o.x = T[tc4 + 0][c]; o.y = T[tc4 + 1][c];
    o.z = T[tc4 + 2][c]; o.w = T[tc4 + 3][c];
    *(ushort4*)(oute + (size_t)(c0 + c) * R + r0 + tc4) = o;
  }
}

// ---------------- grouped GEMM (m97 structure) ----------------
// A: bf16 [NTOK][K] gathered by token list.  Bt: bf16 [E][N][K] (K-contiguous).
// FUSE1: out = bf16 relu(acc + bias) -> outb ; else fp32 acc + bias -> outf.
template <int BM_, int WN_, int MF, int NF, int K, int N, bool FUSE1>
__global__ __launch_bounds__(256) void ffn_kernel(
    const unsigned short* __restrict__ A, const unsigned short* __restrict__ Bt,
    const float* __restrict__ bias, const int* __restrict__ counts,
    const int* __restrict__ lists, unsigned short* __restrict__ outb,
    float* __restrict__ outf) {
  constexpr int BN_ = 16 * NF * WN_;
  constexpr int AISS = BM_ / 64;
  constexpr int BISS = BN_ / 64;
  const int e = blockIdx.z;
  const int cnt = counts[e];
  const int row0 = blockIdx.x * BM_;
  if (row0 >= cnt) return;
  const int col0 = blockIdx.y * BN_;

  __shared__ unsigned short As[BM_][32];
  __shared__ unsigned short Bs[BN_][32];
  __shared__ int toks[BM_];

  const int tid = threadIdx.x;
  const int lane = tid & 63;
  const int w = tid >> 6;
  const int wm = w / WN_;
  const int wn = w % WN_;

  if (tid < BM_) {
    const int r = row0 + tid;
    toks[tid] = (r < cnt) ? lists[e * NTOK + r] : -1;
  }
  __syncthreads();

  // staging geometry: issue i covers LDS bytes [i*4096, i*4096+4096);
  // wave w covers 1024B; lane l -> row = i*64 + w*16 + (l>>2), slot = (l&3)*16B
  const int rsub = lane >> 2;
  const int kslot = (lane & 3) * 8;  // bf16 elems
  const unsigned short* srcA[AISS];
#pragma unroll
  for (int i = 0; i < AISS; ++i) {
    const int t = toks[i * 64 + w * 16 + rsub];
    srcA[i] = A + (size_t)(t < 0 ? 0 : t) * K + kslot;
  }
  const unsigned short* Bte = Bt + (size_t)e * N * K;
  const unsigned short* srcB[BISS];
#pragma unroll
  for (int i = 0; i < BISS; ++i)
    srcB[i] = Bte + (size_t)(col0 + i * 64 + w * 16 + rsub) * K + kslot;

  unsigned short* ldsA[AISS];
#pragma unroll
  for (int i = 0; i < AISS; ++i) ldsA[i] = &As[0][0] + (i * 4096 + w * 1024) / 2;
  unsigned short* ldsB[BISS];
#pragma unroll
  for (int i = 0; i < BISS; ++i) ldsB[i] = &Bs[0][0] + (i * 4096 + w * 1024) / 2;

  f32x4 acc[MF][NF];
#pragma unroll
  for (int m = 0; m < MF; ++m)
#pragma unroll
    for (int n = 0; n < NF; ++n) acc[m][n] = f32x4{0.f, 0.f, 0.f, 0.f};

  const int fr = lane & 15;
  const int fh = (lane >> 4) * 8;

  for (int k0 = 0; k0 < K; k0 += 32) {
#pragma unroll
    for (int i = 0; i < AISS; ++i) load_lds16(srcA[i] + k0, ldsA[i]);
#pragma unroll
    for (int i = 0; i < BISS; ++i) load_lds16(srcB[i] + k0, ldsB[i]);
    __syncthreads();

    s16x8 af[MF], bfr[NF];
#pragma unroll
    for (int m = 0; m < MF; ++m)
      af[m] = *(const s16x8*)&As[wm * MF * 16 + m * 16 + fr][fh];
#pragma unroll
    for (int n = 0; n < NF; ++n)
      bfr[n] = *(const s16x8*)&Bs[wn * NF * 16 + n * 16 + fr][fh];
#pragma unroll
    for (int m = 0; m < MF; ++m)
#pragma unroll
      for (int n = 0; n < NF; ++n)
        acc[m][n] = __builtin_amdgcn_mfma_f32_16x16x32_bf16(af[m], bfr[n],
                                                            acc[m][n], 0, 0, 0);
    __syncthreads();
  }

#pragma unroll
  for (int n = 0; n < NF; ++n) {
    const int col = col0 + wn * NF * 16 + n * 16 + (lane & 15);
    const float bv = bias[e * N + col];
#pragma unroll
    for (int m = 0; m < MF; ++m) {
#pragma unroll
      for (int j = 0; j < 4; ++j) {
        const int r = wm * MF * 16 + m * 16 + (lane >> 4) * 4 + j;
        const int tok = toks[r];
        if (tok >= 0) {
          if (FUSE1) {
            outb[(size_t)tok * N + col] = f2bf(fmaxf(acc[m][n][j] + bv, 0.f));
          } else {
            outf[(size_t)tok * N + col] = acc[m][n][j] + bv;
          }
        }
      }
    }
  }
}

// ================= fallback (round-1 path, needs only ~64.3MB ws) =================
#define BM 128
#define BN 128
#define BK 32
#define LDK 40

__global__ __launch_bounds__(256) void ffn1_old(
    const float* __restrict__ x, const float* __restrict__ W1,
    const float* __restrict__ b1, const int* __restrict__ counts,
    const int* __restrict__ lists, unsigned short* __restrict__ Hbuf) {
  const int e = blockIdx.z;
  const int cnt = counts[e];
  const int row0 = blockIdx.x * BM;
  if (row0 >= cnt) return;
  const int col0 = blockIdx.y * BN;
  __shared__ unsigned short As[BM][LDK];
  __shared__ unsigned short Bs[BN][LDK];
  __shared__ int toks[BM];
  const int tid = threadIdx.x;
  const int lane = tid & 63;
  const int wave = tid >> 6;
  const int wm = wave >> 1;
  const int wn = wave & 1;
  if (tid < BM) {
    const int r = row0 + tid;
    toks[tid] = (r < cnt) ? lists[e * NTOK + r] : -1;
  }
  __syncthreads();
  const float* __restrict__ W1e = W1 + (size_t)e * DDIM * HDIM;
  f32x4 acc[4][4];
#pragma unroll
  for (int m = 0; m < 4; ++m)
#pragma unroll
    for (int n = 0; n < 4; ++n) acc[m][n] = f32x4{0.f, 0.f, 0.f, 0.f};
  const int arow = tid >> 1;
  const int akh = (tid & 1) * 16;
  const int mytok = toks[arow];
  const float* __restrict__ asrc = (mytok >= 0) ? (x + (size_t)mytok * DDIM + akh) : x;
  const int bn = tid >> 1;
  const int bkh = (tid & 1) * 16;
  const float* __restrict__ bsrc = W1e + (size_t)bkh * HDIM + col0 + bn;
  for (int k0 = 0; k0 < DDIM; k0 += BK) {
    u16x8 p0 = {0,0,0,0,0,0,0,0}, p1 = {0,0,0,0,0,0,0,0};
    if (mytok >= 0) {
      const f32x4 f0 = *(const f32x4*)(asrc + k0);
      const f32x4 f1 = *(const f32x4*)(asrc + k0 + 4);
      const f32x4 f2 = *(const f32x4*)(asrc + k0 + 8);
      const f32x4 f3 = *(const f32x4*)(asrc + k0 + 12);
#pragma unroll
      for (int j = 0; j < 4; ++j) {
        p0[j] = f2bf(f0[j]); p0[4 + j] = f2bf(f1[j]);
        p1[j] = f2bf(f2[j]); p1[4 + j] = f2bf(f3[j]);
      }
    }
    u16x8 q0, q1;
    {
      const float* bp = bsrc + (size_t)k0 * HDIM;
#pragma unroll
      for (int kk = 0; kk < 8; ++kk) q0[kk] = f2bf(bp[(size_t)kk * HDIM]);
#pragma unroll
      for (int kk = 0; kk < 8; ++kk) q1[kk] = f2bf(bp[(size_t)(kk + 8) * HDIM]);
    }
    *(u16x8*)&As[arow][akh] = p0;
    *(u16x8*)&As[arow][akh + 8] = p1;
    *(u16x8*)&Bs[bn][bkh] = q0;
    *(u16x8*)&Bs[bn][bkh + 8] = q1;
    __syncthreads();
    s16x8 af[4], bf[4];
#pragma unroll
    for (int m = 0; m < 4; ++m)
      af[m] = *(const s16x8*)&As[wm * 64 + m * 16 + (lane & 15)][(lane >> 4) * 8];
#pragma unroll
    for (int n = 0; n < 4; ++n)
      bf[n] = *(const s16x8*)&Bs[wn * 64 + n * 16 + (lane & 15)][(lane >> 4) * 8];
#pragma unroll
    for (int m = 0; m < 4; ++m)
#pragma unroll
      for (int n = 0; n < 4; ++n)
        acc[m][n] = __builtin_amdgcn_mfma_f32_16x16x32_bf16(af[m], bf[n], acc[m][n], 0, 0, 0);
    __syncthreads();
  }
#pragma unroll
  for (int n = 0; n < 4; ++n) {
    const int col = col0 + wn * 64 + n * 16 + (lane & 15);
    const float bv = b1[e * HDIM + col];
#pragma unroll
    for (int m = 0; m < 4; ++m) {
#pragma unroll
      for (int j = 0; j < 4; ++j) {
        const int r = wm * 64 + m * 16 + (lane >> 4) * 4 + j;
        const int tok = toks[r];
        if (tok >= 0) {
          const float v = fmaxf(acc[m][n][j] + bv, 0.f);
          Hbuf[(size_t)tok * HDIM + col] = f2bf(v);
        }
      }
    }
  }
}

__global__ __launch_bounds__(256) void ffn2_old(
    const unsigned short* __restrict__ Hbuf, const float* __restrict__ W2,
    const float* __restrict__ b2, const int* __restrict__ counts,
    const int* __restrict__ lists, float* __restrict__ out) {
  const int e = blockIdx.z;
  const int cnt = counts[e];
  const int row0 = blockIdx.x * BM;
  if (row0 >= cnt) return;
  const int col0 = blockIdx.y * BN;
  __shared__ unsigned short As[BM][LDK];
  __shared__ unsigned short Bs[BN][LDK];
  __shared__ int toks[BM];
  const int tid = threadIdx.x;
  const int lane = tid & 63;
  const int wave = tid >> 6;
  const int wm = wave >> 1;
  const int wn = wave & 1;
  if (tid < BM) {
    const int r = row0 + tid;
    toks[tid] = (r < cnt) ? lists[e * NTOK + r] : -1;
  }
  __syncthreads();
  f32x4 acc[4][4];
#pragma unroll
  for (int m = 0; m < 4; ++m)
#pragma unroll
    for (int n = 0; n < 4; ++n) acc[m][n] = f32x4{0.f, 0.f, 0.f, 0.f};
  const int arow = tid >> 1;
  const int akh = (tid & 1) * 16;
  const int mytok = toks[arow];
  const unsigned short* __restrict__ asrc =
      (mytok >= 0) ? (Hbuf + (size_t)mytok * HDIM + akh) : Hbuf;
  const int bn = tid >> 1;
  const int bkh = (tid & 1) * 16;
  const float* __restrict__ bsrc =
      W2 + (size_t)e * HDIM * DDIM + (size_t)bkh * DDIM + col0 + bn;
  for (int k0 = 0; k0 < HDIM; k0 += BK) {
    u16x8 p0 = {0,0,0,0,0,0,0,0}, p1 = {0,0,0,0,0,0,0,0};
    if (mytok >= 0) {
      p0 = *(const u16x8*)(asrc + k0);
      p1 = *(const u16x8*)(asrc + k0 + 8);
    }
    u16x8 q0, q1;
    {
      const float* bp = bsrc + (size_t)k0 * DDIM;
#pragma unroll
      for (int kk = 0; kk < 8; ++kk) q0[kk] = f2bf(bp[(size_t)kk * DDIM]);
#pragma unroll
      for (int kk = 0; kk < 8; ++kk) q1[kk] = f2bf(bp[(size_t)(kk + 8) * DDIM]);
    }
    *(u16x8*)&As[arow][akh] = p0;
    *(u16x8*)&As[arow][akh + 8] = p1;
    *(u16x8*)&Bs[bn][bkh] = q0;
    *(u16x8*)&Bs[bn][bkh + 8] = q1;
    __syncthreads();
    s16x8 af[4], bf[4];
#pragma unroll
    for (int m = 0; m < 4; ++m)
      af[m] = *(const s16x8*)&As[wm * 64 + m * 16 + (lane & 15)][(lane >> 4) * 8];
#pragma unroll
    for (int n = 0; n < 4; ++n)
      bf[n] = *(const s16x8*)&Bs[wn * 64 + n * 16 + (lane & 15)][(lane >> 4) * 8];
#pragma unroll
    for (int m = 0; m < 4; ++m)
#pragma unroll
      for (int n = 0; n < 4; ++n)
        acc[m][n] = __builtin_amdgcn_mfma_f32_16x16x32_bf16(af[m], bf[n], acc[m][n], 0, 0, 0);
    __syncthreads();
  }
#pragma unroll
  for (int n = 0; n < 4; ++n) {
    const int col = col0 + wn * 64 + n * 16 + (lane & 15);
    const float bv = b2[e * DDIM + col];
#pragma unroll
    for (int m = 0; m < 4; ++m) {
#pragma unroll
      for (int j = 0; j < 4; ++j) {
        const int r = wm * 64 + m * 16 + (lane >> 4) * 4 + j;
        const int tok = toks[r];
        if (tok >= 0) out[(size_t)tok * DDIM + col] = acc[m][n][j] + bv;
      }
    }
  }
}

extern "C" void kernel_launch(void* const* d_in, const int* in_sizes, int n_in,
                              void* d_out, int out_size, void* d_ws, size_t ws_size,
                              hipStream_t stream) {
  (void)in_sizes; (void)n_in; (void)out_size;
  const float* x  = (const float*)d_in[0];
  const float* Wg = (const float*)d_in[1];
  const float* bg = (const float*)d_in[2];
  const float* W1 = (const float*)d_in[3];
  const float* b1 = (const float*)d_in[4];
  const float* W2 = (const float*)d_in[5];
  const float* b2 = (const float*)d_in[6];
  float* out = (float*)d_out;

  char* ws = (char*)d_ws;
  const size_t SZ_CNT = 256;
  const size_t SZ_LST = (size_t)NEXP * NTOK * sizeof(int);              // 256 KB
  const size_t SZ_XB  = (size_t)NTOK * DDIM * 2;                        // 16 MB
  const size_t SZ_H   = (size_t)NTOK * HDIM * 2;                        // 64 MB
  const size_t SZ_WT  = (size_t)NEXP * DDIM * HDIM * 2;                 // 64 MB

  int* counts = (int*)ws;
  int* lists  = (int*)(ws + SZ_CNT);

  const size_t need_new = SZ_CNT + SZ_LST + SZ_XB + SZ_H + SZ_WT;
  const size_t need_old = SZ_CNT + SZ_LST + SZ_H;

  if (ws_size >= need_new) {
    unsigned short* xb   = (unsigned short*)(ws + SZ_CNT + SZ_LST);
    unsigned short* Hbuf = (unsigned short*)(ws + SZ_CNT + SZ_LST + SZ_XB);
    unsigned short* Wt   = (unsigned short*)(ws + SZ_CNT + SZ_LST + SZ_XB + SZ_H);

    hipMemsetAsync(counts, 0, SZ_CNT, stream);
    gate_kernel<<<NTOK / 4, 256, 0, stream>>>(x, Wg, bg, counts, lists);
    conv_bf16_kernel<<<(NTOK * DDIM) / (8 * 256), 256, 0, stream>>>(x, xb);
    // W1 [E][D][H] -> Wt [E][H][D]
    transpose_conv_kernel<<<dim3(HDIM / 64, DDIM / 64, NEXP), 256, 0, stream>>>(
        W1, Wt, DDIM, HDIM);
    ffn_kernel<128, 2, 4, 4, DDIM, HDIM, true>
        <<<dim3(NTOK / 128, HDIM / 128, NEXP), 256, 0, stream>>>(
            xb, Wt, b1, counts, lists, Hbuf, nullptr);
    // W2 [E][H][D] -> Wt [E][D][H]  (reuses the same buffer, after ffn1)
    transpose_conv_kernel<<<dim3(DDIM / 64, HDIM / 64, NEXP), 256, 0, stream>>>(
        W2, Wt, HDIM, DDIM);
    ffn_kernel<64, 4, 4, 2, HDIM, DDIM, false>
        <<<dim3(NTOK / 64, DDIM / 128, NEXP), 256, 0, stream>>>(
            Hbuf, Wt, b2, counts, lists, nullptr, out);
  } else if (ws_size >= need_old) {
    unsigned short* Hbuf = (unsigned short*)(ws + SZ_CNT + SZ_LST);
    hipMemsetAsync(counts, 0, SZ_CNT, stream);
    gate_kernel<<<NTOK / 4, 256, 0, stream>>>(x, Wg, bg, counts, lists);
    ffn1_old<<<dim3(NTOK / BM, HDIM / BN, NEXP), 256, 0, stream>>>(
        x, W1, b1, counts, lists, Hbuf);
    ffn2_old<<<dim3(NTOK / BM, DDIM / BN, NEXP), 256, 0, stream>>>(
        Hbuf, W2, b2, counts, lists, out);
  }
}